// Round 8
// baseline (1331.986 us; speedup 1.0000x reference)
//
#include <hip/hip_runtime.h>
#include <hip/hip_fp16.h>
#include <math.h>

// Problem constants (from reference): N=100000, E=1600000, F_IN=8, H=128,
// L=4, E_FEAT=16, G=256, OUT=256. N/E derived from in_sizes at launch.
#define GG 256

typedef __attribute__((ext_vector_type(8))) short short8;
typedef __attribute__((ext_vector_type(4))) float f32x4;
typedef _Float16 half4v __attribute__((ext_vector_type(4)));
typedef __attribute__((ext_vector_type(8))) unsigned uint8v;

__device__ __forceinline__ unsigned short f2bf(float x) {
  union { float f; unsigned u; } v; v.f = x;
  unsigned r = v.u + 0x7fff + ((v.u >> 16) & 1);   // round-to-nearest-even
  return (unsigned short)(r >> 16);
}

__device__ __forceinline__ unsigned pack_h2(float a, float b) {
  __half2 h = __floats2half2_rn(a, b);
  return *(unsigned*)&h;
}

// scalar load (wave-uniform address) — SMEM path, SALU addressing
__device__ __forceinline__ uint8v sload8(const void* p) {
  uint8v r;
  asm volatile("s_load_dwordx8 %0, %1, 0x0"
               : "=s"(r) : "s"((unsigned long long)p));
  return r;
}
// drain SMEM with the pending registers tied THROUGH the asm ("+s"), so any
// consumer/copy of them is ordered after the waitcnt (SGPR-read-race safe).
__device__ __forceinline__ void swait2(uint8v& a, uint8v& b) {
  asm volatile("s_waitcnt lgkmcnt(0)" : "+s"(a), "+s"(b) :: "memory");
  __builtin_amdgcn_sched_barrier(0);
}

// ---------- h = x @ emb_W + emb_b  ([N,8]@[8,128]); also writes bf16 shadow ----------
__global__ __launch_bounds__(256) void k_emb(const float* __restrict__ x,
    const float* __restrict__ W, const float* __restrict__ b,
    float* __restrict__ h, unsigned short* __restrict__ hb, int N) {
  int idx = blockIdx.x * 256 + threadIdx.x;      // one float4 of output per thread
  if (idx >= N * 32) return;
  int n = idx >> 5, q = idx & 31;
  const float* xr = x + (size_t)n * 8;
  float xs[8];
#pragma unroll
  for (int k = 0; k < 8; ++k) xs[k] = xr[k];
  float4 acc = ((const float4*)b)[q];
#pragma unroll
  for (int k = 0; k < 8; ++k) {
    float4 w = ((const float4*)(W + (size_t)k * 128))[q];
    acc.x += xs[k] * w.x; acc.y += xs[k] * w.y;
    acc.z += xs[k] * w.z; acc.w += xs[k] * w.w;
  }
  ((float4*)h)[idx] = acc;
  ushort4 hv4 = make_ushort4(f2bf(acc.x), f2bf(acc.y), f2bf(acc.z), f2bf(acc.w));
  *(ushort4*)(hb + (size_t)idx * 4) = hv4;
}

// ---------- edge weights -> MFMA B-fragment order (fp16) ----------
// eWf[l][nt][lane] = 2 uints = 4 halves: W[l][quad*4+i][nt*16+l15], i=0..3
__global__ __launch_bounds__(256) void k_wconv2(const float* __restrict__ eW,
    unsigned* __restrict__ eWf) {              // 4*8*64 uint2 = 4096 uints
  int i = blockIdx.x * 256 + threadIdx.x;      // one uint2 per thread
  if (i >= 2048) return;
  int lane = i & 63, nt = (i >> 6) & 7, l = i >> 9;
  int l15 = lane & 15, quad = lane >> 4;
  const float* base = eW + (size_t)l * 16 * 128 + (size_t)(nt * 16 + l15);
  unsigned lo = pack_h2(base[(quad * 4 + 0) * 128], base[(quad * 4 + 1) * 128]);
  unsigned hi = pack_h2(base[(quad * 4 + 2) * 128], base[(quad * 4 + 3) * 128]);
  eWf[(size_t)i * 2] = lo;
  eWf[(size_t)i * 2 + 1] = hi;
}

// ---------- transpose nn_W to bf16: WT[l][n][k] = bf16(nn_W[l][k][n]) ----------
__global__ __launch_bounds__(256) void k_nnconv(const float* __restrict__ W,
    unsigned short* __restrict__ WT) {
  int i = blockIdx.x * 256 + threadIdx.x;    // i = ((l*128)+k)*128 + n
  if (i >= 4 * 128 * 128) return;
  int n = i & 127, k = (i >> 7) & 127, l = i >> 14;
  WT[((size_t)(l * 128 + n)) * 128 + k] = f2bf(W[i]);
}

// ---------- CSR build ----------
__global__ void k_hist(const int* __restrict__ dst, int* __restrict__ deg, int E) {
  int e = blockIdx.x * blockDim.x + threadIdx.x;
  if (e < E) atomicAdd(&deg[dst[e]], 1);
}

__global__ __launch_bounds__(256) void k_scan_reduce(const int* __restrict__ deg,
    int* __restrict__ bsum, int N) {
  __shared__ int sd[256];
  int i = blockIdx.x * 256 + threadIdx.x;
  sd[threadIdx.x] = (i < N) ? deg[i] : 0;
  __syncthreads();
  for (int s = 128; s > 0; s >>= 1) {
    if (threadIdx.x < s) sd[threadIdx.x] += sd[threadIdx.x + s];
    __syncthreads();
  }
  if (threadIdx.x == 0) bsum[blockIdx.x] = sd[0];
}

// single-block exclusive scan over nb (<=512) block sums
__global__ __launch_bounds__(512) void k_scan_mid(int* bsum, int nb) {
  __shared__ int sd[512];
  int t = threadIdx.x;
  int v = (t < nb) ? bsum[t] : 0;
  sd[t] = v; __syncthreads();
  for (int d = 1; d < 512; d <<= 1) {
    int xv = (t >= d) ? sd[t - d] : 0;
    __syncthreads();
    sd[t] += xv;
    __syncthreads();
  }
  if (t < nb) bsum[t] = sd[t] - v;   // exclusive
}

__global__ __launch_bounds__(256) void k_scan_final(const int* __restrict__ deg,
    const int* __restrict__ bsum, int* __restrict__ offs,
    int* __restrict__ cursor, int N) {
  __shared__ int sd[256];
  int t = threadIdx.x;
  int i = blockIdx.x * 256 + t;
  int v = (i < N) ? deg[i] : 0;
  sd[t] = v; __syncthreads();
  for (int d = 1; d < 256; d <<= 1) {           // Hillis-Steele inclusive scan
    int xv = (t >= d) ? sd[t - d] : 0;
    __syncthreads();
    sd[t] += xv;
    __syncthreads();
  }
  int off = bsum[blockIdx.x] + sd[t] - v;       // exclusive
  if (i < N) {
    offs[i] = off; cursor[i] = off;
    if (i == N - 1) offs[N] = off + v;
  }
}

// fill CSR: permute src + attr (converted to fp16, 32 B/edge) into dst order
__global__ void k_fill(const int* __restrict__ src, const int* __restrict__ dst,
    const float* __restrict__ attr, int* __restrict__ cursor,
    int* __restrict__ csrc, uint4* __restrict__ cattr16, int E) {
  int e = blockIdx.x * blockDim.x + threadIdx.x;
  if (e >= E) return;
  int d = dst[e];
  int pos = atomicAdd(&cursor[d], 1);
  csrc[pos] = src[e];
  const float4* a = (const float4*)(attr + (size_t)e * 16);
  float4 a0 = a[0], a1 = a[1], a2 = a[2], a3 = a[3];
  uint4 o0, o1;
  o0.x = pack_h2(a0.x, a0.y); o0.y = pack_h2(a0.z, a0.w);
  o0.z = pack_h2(a1.x, a1.y); o0.w = pack_h2(a1.z, a1.w);
  o1.x = pack_h2(a2.x, a2.y); o1.y = pack_h2(a2.z, a2.w);
  o1.z = pack_h2(a3.x, a3.y); o1.w = pack_h2(a3.z, a3.w);
  cattr16[(size_t)pos * 2] = o0;
  cattr16[(size_t)pos * 2 + 1] = o1;
}

// ---------- graph boundaries (batch is sorted) ----------
__global__ void k_gstart(const int* __restrict__ batch, int* __restrict__ gstart,
                         int N, int Gn) {
  int i = blockIdx.x * blockDim.x + threadIdx.x;
  if (i >= N) return;
  int b = batch[i];
  if (i == 0) { for (int g = 0; g <= b; ++g) gstart[g] = 0; }
  else { int bp = batch[i - 1]; for (int g = bp + 1; g <= b; ++g) gstart[g] = i; }
  if (i == N - 1) { for (int g = b + 1; g <= Gn; ++g) gstart[g] = N; }
}

// ---------- fused edge embed + gather + relu + aggregate (v7, cstats removed) ----------
__global__ __launch_bounds__(256) void k_edge_agg(const float* __restrict__ h,
    const unsigned* __restrict__ hb32,       // bf16 shadow viewed as uint
    const uint4* __restrict__ cattr16, const int* __restrict__ csrc,
    const int* __restrict__ offs, const unsigned* __restrict__ eWf,
    const float* __restrict__ eb, unsigned* __restrict__ hpa16, int N) {
  __shared__ __half elds_all[4][16 * 136];
  int t = threadIdx.x;
  int lane = t & 63;                        // lane -> columns 2*lane, 2*lane+1
  int l15 = lane & 15, quad = lane >> 4;
  int wid = blockIdx.x * 4 + (t >> 6);
  int nw = gridDim.x * 4;
  __half* elds = elds_all[t >> 6];
  uint2 bfr[8];                             // B-fragments (whole W in regs)
#pragma unroll
  for (int nt = 0; nt < 8; ++nt) bfr[nt] = ((const uint2*)eWf)[nt * 64 + lane];
  float2 bias = *(const float2*)(eb + 2 * lane);
  const unsigned* hb_l = hb32 + lane;       // + s*64 per edge (row = 64 uints)

#define GI(r, SC)                                                           \
  unsigned u##r = 0;                                                        \
  if (j0 + (r) < je) u##r = hb_l[(size_t)(unsigned)(SC) * 64];

#define EPI(r, UU, AX, AY)                                                  \
  if (j0 + (r) < je) {                                                      \
    __half2 ev2 = *(__half2*)&elds[(r) * 136 + 2 * lane];                   \
    union { unsigned uu; float ff; } c0, c1;                                \
    c0.uu = (UU) << 16; c1.uu = (UU) & 0xffff0000u;                         \
    AX += fmaxf(__low2float(ev2) + bias.x + c0.ff, 0.f);                    \
    AY += fmaxf(__high2float(ev2) + bias.y + c1.ff, 0.f);                   \
  }

#define LOADA(DST, J0)                                                      \
  DST = *(const uint2*)((const char*)cattr16 +                              \
        ((size_t)(unsigned)((J0) + l15)) * 32 + quad * 8);

  for (int n = wid; n < N; n += nw) {
    int jb = __builtin_amdgcn_readfirstlane(offs[n]);
    int je = __builtin_amdgcn_readfirstlane(offs[n + 1]);
    float ax = 0.f, ay = 0.f, bx = 0.f, by = 0.f;
    if (jb < je) {
      uint8v scA = sload8((const char*)csrc + ((size_t)(unsigned)jb << 2));
      uint8v scB = sload8((const char*)csrc + ((size_t)(unsigned)(jb + 8) << 2));
      uint2 araw;
      LOADA(araw, jb)
      swait2(scA, scB);
      for (int j0 = jb;;) {
        GI(0, scA[0]) GI(1, scA[1]) GI(2, scA[2]) GI(3, scA[3])
        GI(4, scA[4]) GI(5, scA[5]) GI(6, scA[6]) GI(7, scA[7])
        GI(8, scB[0]) GI(9, scB[1]) GI(10, scB[2]) GI(11, scB[3])
        GI(12, scB[4]) GI(13, scB[5]) GI(14, scB[6]) GI(15, scB[7])
        bool more = (j0 + 16 < je);
        uint8v scA2, scB2;
        uint2 araw2;
        if (more) {
          scA2 = sload8((const char*)csrc + ((size_t)(unsigned)(j0 + 16) << 2));
          scB2 = sload8((const char*)csrc + ((size_t)(unsigned)(j0 + 24) << 2));
          LOADA(araw2, j0 + 16)
        }
        half4v av;
        __builtin_memcpy(&av, &araw, 8);
        f32x4 ee[8];
#pragma unroll
        for (int nt = 0; nt < 8; ++nt) {
          half4v bv;
          __builtin_memcpy(&bv, &bfr[nt], 8);
          ee[nt] = __builtin_amdgcn_mfma_f32_16x16x16f16(
              av, bv, (f32x4){0.f, 0.f, 0.f, 0.f}, 0, 0, 0);
        }
#pragma unroll
        for (int nt = 0; nt < 8; ++nt)
#pragma unroll
          for (int reg = 0; reg < 4; ++reg)
            elds[(quad * 4 + reg) * 136 + nt * 16 + l15] =
                __float2half(ee[nt][reg]);
        EPI(0, u0, ax, ay)  EPI(1, u1, bx, by)
        EPI(2, u2, ax, ay)  EPI(3, u3, bx, by)
        EPI(4, u4, ax, ay)  EPI(5, u5, bx, by)
        EPI(6, u6, ax, ay)  EPI(7, u7, bx, by)
        EPI(8, u8, ax, ay)  EPI(9, u9, bx, by)
        EPI(10, u10, ax, ay) EPI(11, u11, bx, by)
        EPI(12, u12, ax, ay) EPI(13, u13, bx, by)
        EPI(14, u14, ax, ay) EPI(15, u15, bx, by)
        j0 += 16;
        if (!more) break;
        swait2(scA2, scB2);
        scA = scA2; scB = scB2; araw = araw2;
      }
    }
    float2 hvv = *(const float2*)(h + (size_t)n * 128 + 2 * lane);
    float rx = hvv.x + ax + bx;
    float ry = hvv.y + ay + by;
    hpa16[(size_t)n * 64 + lane] = ((unsigned)f2bf(ry) << 16) | (unsigned)f2bf(rx);
  }
#undef GI
#undef EPI
#undef LOADA
}

// ---------- k_cov: S = hpa^T hpa (raw sums, 128x128 f32) + colsum(hpa) ----------
// 128 blocks x 256 thr (4 waves). Per 32-node k-step: stage [32][140] bf16 tile,
// transposed u16 frag reads (lane=feat, elems=8 nodes; A/B frag layouts are the
// same pattern), wave w computes row-groups {2w,2w+1} x all 8 col-groups via
// 16x mfma_16x16x32_bf16. Partials atomicAdd'd to S. Colsum fused into staging.
__global__ __launch_bounds__(256) void k_cov(const uint4* __restrict__ hpa4,
    float* __restrict__ S, float* __restrict__ csum, int N) {
  __shared__ __align__(16) short tile[32 * 140];
  __shared__ float scr[128 * 33];
  int t = threadIdx.x;
  int lane = t & 63, w = t >> 6;
  int l15 = lane & 15, quad = lane >> 4;
  int nl = t >> 3, seg = t & 7;
  int chunk = (((N + 127) / 128) + 31) & ~31;
  int base = blockIdx.x * chunk;
  int nsteps = chunk / 32;
  float cs[16];
#pragma unroll
  for (int i = 0; i < 16; ++i) cs[i] = 0.f;
  f32x4 acc[2][8];
#pragma unroll
  for (int i = 0; i < 2; ++i)
#pragma unroll
    for (int j = 0; j < 8; ++j) acc[i][j] = (f32x4){0.f, 0.f, 0.f, 0.f};
  int w2 = w * 2;
  for (int ks = 0; ks < nsteps; ++ks) {
    int node = base + ks * 32 + nl;
    uint4 a = make_uint4(0, 0, 0, 0), b = make_uint4(0, 0, 0, 0);
    if (node < N) {
      a = hpa4[(size_t)node * 16 + seg * 2];
      b = hpa4[(size_t)node * 16 + seg * 2 + 1];
    }
    __syncthreads();            // previous step's reads complete
    *(uint2*)&tile[nl * 140 + seg * 16]      = make_uint2(a.x, a.y);
    *(uint2*)&tile[nl * 140 + seg * 16 + 4]  = make_uint2(a.z, a.w);
    *(uint2*)&tile[nl * 140 + seg * 16 + 8]  = make_uint2(b.x, b.y);
    *(uint2*)&tile[nl * 140 + seg * 16 + 12] = make_uint2(b.z, b.w);
    unsigned uu[8] = {a.x, a.y, a.z, a.w, b.x, b.y, b.z, b.w};
#pragma unroll
    for (int k = 0; k < 8; ++k) {
      union { unsigned u; float f; } lo, hi;
      lo.u = uu[k] << 16; hi.u = uu[k] & 0xffff0000u;
      cs[2 * k] += lo.f; cs[2 * k + 1] += hi.f;
    }
    __syncthreads();
    short8 fb[8];               // B-frags: all 8 col feature-groups
#pragma unroll
    for (int g = 0; g < 8; ++g)
#pragma unroll
      for (int e = 0; e < 8; ++e)
        fb[g][e] = tile[(quad * 8 + e) * 140 + g * 16 + l15];
    short8 fa0, fa1;            // A-frags: this wave's row groups (static idx)
#pragma unroll
    for (int e = 0; e < 8; ++e) {
      fa0[e] = tile[(quad * 8 + e) * 140 + w2 * 16 + l15];
      fa1[e] = tile[(quad * 8 + e) * 140 + (w2 + 1) * 16 + l15];
    }
#pragma unroll
    for (int j = 0; j < 8; ++j) {
      acc[0][j] = __builtin_amdgcn_mfma_f32_16x16x32_bf16(fa0, fb[j], acc[0][j], 0, 0, 0);
      acc[1][j] = __builtin_amdgcn_mfma_f32_16x16x32_bf16(fa1, fb[j], acc[1][j], 0, 0, 0);
    }
  }
#pragma unroll
  for (int i = 0; i < 2; ++i)
#pragma unroll
    for (int j = 0; j < 8; ++j)
#pragma unroll
      for (int reg = 0; reg < 4; ++reg) {
        int row = (w2 + i) * 16 + quad * 4 + reg;
        atomicAdd(&S[(size_t)row * 128 + j * 16 + l15], acc[i][j][reg]);
      }
  __syncthreads();
#pragma unroll
  for (int f = 0; f < 16; ++f) scr[(seg * 16 + f) * 33 + nl] = cs[f];
  __syncthreads();
  if (t < 128) {
    float s = 0.f;
#pragma unroll 8
    for (int k = 0; k < 32; ++k) s += scr[t * 33 + k];
    atomicAdd(&csum[t], s);
  }
}

// ---------- k_stats: mu[c], rstd[c] from S, csum, bf16 W (consistent w/ MFMA) ----------
// mu_c = (csum . w_c)/N + b_c ; var_c = (w_c^T S w_c)/N - ((csum.w_c)/N)^2
__global__ __launch_bounds__(128) void k_stats(const float* __restrict__ S,
    const float* __restrict__ csum, const unsigned short* __restrict__ WT,
    const float* __restrict__ bias, float* __restrict__ must,
    float* __restrict__ rstds, int N) {
  __shared__ float wv[128];
  __shared__ double red[128];
  __shared__ double red2[128];
  int c = blockIdx.x, r = threadIdx.x;
  union { unsigned u; float f; } wc;
  wc.u = (unsigned)WT[(size_t)c * 128 + r] << 16;   // bf16(W[r][c])
  wv[r] = wc.f;
  __syncthreads();
  const float* Sr = S + (size_t)r * 128;
  double dr = 0.0;
#pragma unroll 8
  for (int k = 0; k < 128; ++k) dr += (double)Sr[k] * (double)wv[k];
  red[r] = dr * (double)wv[r];
  red2[r] = (double)csum[r] * (double)wv[r];
  __syncthreads();
  for (int s = 64; s > 0; s >>= 1) {
    if (r < s) { red[r] += red[r + s]; red2[r] += red2[r + s]; }
    __syncthreads();
  }
  if (r == 0) {
    double invN = 1.0 / (double)N;
    double m0 = red2[0] * invN;
    double var = red[0] * invN - m0 * m0;
    if (var < 0.0) var = 0.0;
    must[c] = (float)(m0 + (double)bias[c]);
    rstds[c] = (float)(1.0 / sqrt(var + 1e-5));
  }
}

// ---------- fused MFMA node GEMM + BN apply + GELU + residual ----------
// hc never materialized: acc stays in regs -> LDS bounce [128][132] f32 ->
// coalesced float4 BN/GELU/residual epilogue writing h (+ bf16 shadow hb).
__global__ __launch_bounds__(256) void k_gemm_mfma(
    const unsigned short* __restrict__ A16, const unsigned short* __restrict__ WT16,
    const float* __restrict__ bias, const float* __restrict__ must,
    const float* __restrict__ rstds, const float* __restrict__ g,
    const float* __restrict__ bb, float* __restrict__ h,
    unsigned short* __restrict__ hb, int N) {
  __shared__ __align__(16) char smem[69632];
  short* a_lds = (short*)smem;
  short* w_lds = (short*)(smem + 34816);
  int t = threadIdx.x;
  int rowbase = blockIdx.x * 128;
  {
    int r = t >> 1;
    int off = (t & 1) * 64;              // shorts
    const short* ga = (const short*)A16 + (size_t)(rowbase + r) * 128 + off;
    short* la = &a_lds[r * 136 + off];
    const short* gw = (const short*)WT16 + (size_t)r * 128 + off;
    short* lw = &w_lds[r * 136 + off];
    if (rowbase + r < N) {
#pragma unroll
      for (int jj = 0; jj < 8; ++jj)
        *(uint4*)(la + jj * 8) = *(const uint4*)(ga + jj * 8);
    } else {
#pragma unroll
      for (int jj = 0; jj < 8; ++jj)
        *(uint4*)(la + jj * 8) = make_uint4(0, 0, 0, 0);
    }
#pragma unroll
    for (int jj = 0; jj < 8; ++jj)
      *(uint4*)(lw + jj * 8) = *(const uint4*)(gw + jj * 8);
  }
  __syncthreads();
  int w = t >> 6;
  int lane = t & 63;
  int l15 = lane & 15, quad = lane >> 4;
  f32x4 acc[2][8];
#pragma unroll
  for (int rt = 0; rt < 2; ++rt)
#pragma unroll
    for (int nt = 0; nt < 8; ++nt)
      acc[rt][nt] = (f32x4){0.f, 0.f, 0.f, 0.f};
#pragma unroll
  for (int kc = 0; kc < 4; ++kc) {
    int k0 = kc * 32 + quad * 8;
    short8 af0 = *(const short8*)&a_lds[(w * 32 + l15) * 136 + k0];
    short8 af1 = *(const short8*)&a_lds[(w * 32 + 16 + l15) * 136 + k0];
#pragma unroll
    for (int nt = 0; nt < 8; ++nt) {
      short8 bf = *(const short8*)&w_lds[(nt * 16 + l15) * 136 + k0];
      acc[0][nt] = __builtin_amdgcn_mfma_f32_16x16x32_bf16(af0, bf, acc[0][nt], 0, 0, 0);
      acc[1][nt] = __builtin_amdgcn_mfma_f32_16x16x32_bf16(af1, bf, acc[1][nt], 0, 0, 0);
    }
  }
  __syncthreads();                     // staging LDS now free
  float* fb = (float*)smem;            // [128][132] f32 = 67584 B
#pragma unroll
  for (int nt = 0; nt < 8; ++nt) {
    int col = nt * 16 + l15;
    float bv = bias[col];
#pragma unroll
    for (int rt = 0; rt < 2; ++rt) {
      int rl = w * 32 + rt * 16 + quad * 4;
#pragma unroll
      for (int reg = 0; reg < 4; ++reg)
        fb[(rl + reg) * 132 + col] = acc[rt][nt][reg] + bv;
    }
  }
  __syncthreads();
  int r2 = t >> 1, halfp = t & 1;
  int grow = rowbase + r2;
  if (grow < N) {
    float4* hrow = (float4*)(h + (size_t)grow * 128);
    ushort4* hbrow = hb ? (ushort4*)(hb + (size_t)grow * 128) : (ushort4*)0;
#pragma unroll 4
    for (int i = 0; i < 16; ++i) {
      int c4 = halfp * 16 + i;
      float4 v = *(float4*)&fb[r2 * 132 + c4 * 4];
      float4 m4 = ((const float4*)must)[c4];
      float4 s4 = ((const float4*)rstds)[c4];
      float4 g4 = ((const float4*)g)[c4];
      float4 b4 = ((const float4*)bb)[c4];
      float4 hv = hrow[c4];
#define BN1(X)                                                       \
      { float xn = (v.X - m4.X) * s4.X * g4.X + b4.X;                \
        hv.X += 0.5f * xn * (1.f + erff(xn * 0.70710678118654752f)); }
      BN1(x) BN1(y) BN1(z) BN1(w)
#undef BN1
      hrow[c4] = hv;
      if (hbrow)
        hbrow[c4] = make_ushort4(f2bf(hv.x), f2bf(hv.y), f2bf(hv.z), f2bf(hv.w));
    }
  }
}

// ---------- rep[g] = (sum over nodes of graph g of h[n]) @ lin_W + cnt*lin_b ----------
__global__ __launch_bounds__(256) void k_poolfinal(const float* __restrict__ h,
    const int* __restrict__ gstart, const float* __restrict__ W,
    const float* __restrict__ b, float* __restrict__ out) {
  int g = blockIdx.x;
  int t = threadIdx.x, c = t & 127, half = t >> 7;
  int n0 = gstart[g], n1 = gstart[g + 1];
  float s = 0.f;
  for (int n = n0 + half; n < n1; n += 2) s += h[(size_t)n * 128 + c];
  __shared__ float ls[256];
  __shared__ float pr[128];
  ls[t] = s; __syncthreads();
  if (t < 128) pr[t] = ls[t] + ls[t + 128];
  __syncthreads();
  float cnt = (float)(n1 - n0);
  float acc = cnt * b[t];
#pragma unroll 8
  for (int k = 0; k < 128; ++k) acc += pr[k] * W[(size_t)k * 256 + t];
  out[(size_t)g * 256 + t] = acc;
}

extern "C" void kernel_launch(void* const* d_in, const int* in_sizes, int n_in,
                              void* d_out, int out_size, void* d_ws, size_t ws_size,
                              hipStream_t stream) {
  const float* x     = (const float*)d_in[0];
  const int*   eidx  = (const int*)d_in[1];
  const float* eattr = (const float*)d_in[2];
  const int*   batch = (const int*)d_in[3];
  const float* embW  = (const float*)d_in[4];
  const float* embB  = (const float*)d_in[5];
  const float* edgeW = (const float*)d_in[6];
  const float* edgeB = (const float*)d_in[7];
  const float* nnW   = (const float*)d_in[8];
  const float* nnB   = (const float*)d_in[9];
  const float* bnG   = (const float*)d_in[10];
  const float* bnB   = (const float*)d_in[11];
  const float* linW  = (const float*)d_in[12];
  const float* linB  = (const float*)d_in[13];
  float* out = (float*)d_out;

  int N = in_sizes[0] / 8;
  int E = in_sizes[1] / 2;
  const int* src = eidx;
  const int* dst = eidx + E;

  // workspace carve-up; cattr16/csrc get 16-edge slack for masked group loads.
  char* wptr = (char*)d_ws;
  auto alloc = [&](size_t bytes) {
    char* p = wptr; wptr += (bytes + 255) & ~(size_t)255; return p;
  };
  float* h      = (float*)alloc((size_t)N * 128 * 4);
  unsigned short* hb = (unsigned short*)alloc((size_t)N * 128 * 2);  // bf16 h shadow
  unsigned* hpa16 = (unsigned*)alloc((size_t)N * 64 * 4);  // bf16 h+agg (GEMM input)
  uint4* cattr16 = (uint4*)alloc((size_t)E * 32 + 1024); // fp16 attrs + slack
  int*   csrc   = (int*)alloc((size_t)E * 4 + 256);      // + slack
  int*   offs   = (int*)alloc((size_t)(N + 1) * 4);
  int*   cursor = (int*)alloc((size_t)N * 4);
  int*   deg    = (int*)alloc((size_t)N * 4);
  int nb = (N + 255) / 256;
  int*   bsum   = (int*)alloc((size_t)nb * 4);
  float* S      = (float*)alloc(128 * 128 * 4);          // hpa^T hpa raw sums
  float* csum   = (float*)alloc(128 * 4);                // colsum(hpa) (contig w/ S)
  float* must   = (float*)alloc(128 * 4);                // BN mu per col
  float* rstds  = (float*)alloc(128 * 4);                // BN rstd per col
  unsigned* eWf = (unsigned*)alloc(4096 * 4);            // [4][8][64] B-frag uint2
  unsigned short* WT16 = (unsigned short*)alloc(4 * 128 * 128 * 2);  // bf16 W^T
  int*   gstart = (int*)alloc((size_t)(GG + 1) * 4);

  int q32 = (N * 32 + 255) / 256;

  hipMemsetAsync(deg, 0, (size_t)N * 4, stream);
  k_emb<<<q32, 256, 0, stream>>>(x, embW, embB, h, hb, N);
  k_wconv2<<<8, 256, 0, stream>>>(edgeW, eWf);
  k_nnconv<<<256, 256, 0, stream>>>(nnW, WT16);
  k_hist<<<(E + 255) / 256, 256, 0, stream>>>(dst, deg, E);
  k_scan_reduce<<<nb, 256, 0, stream>>>(deg, bsum, N);
  k_scan_mid<<<1, 512, 0, stream>>>(bsum, nb);
  k_scan_final<<<nb, 256, 0, stream>>>(deg, bsum, offs, cursor, N);
  k_fill<<<(E + 255) / 256, 256, 0, stream>>>(src, dst, eattr, cursor, csrc, cattr16, E);
  k_gstart<<<(N + 255) / 256, 256, 0, stream>>>(batch, gstart, N, GG);

  int gblk = (N + 127) / 128;
  for (int l = 0; l < 4; ++l) {
    hipMemsetAsync(S, 0, 128 * 128 * 4 + 512, stream);   // S + csum (contiguous)
    k_edge_agg<<<8192, 256, 0, stream>>>(h, (const unsigned*)hb, cattr16, csrc,
        offs, eWf + (size_t)l * 1024, edgeB + (size_t)l * 128, hpa16, N);
    k_cov<<<128, 256, 0, stream>>>((const uint4*)hpa16, S, csum, N);
    k_stats<<<128, 128, 0, stream>>>(S, csum, WT16 + (size_t)l * 128 * 128,
        nnB + (size_t)l * 128, must, rstds, N);
    k_gemm_mfma<<<gblk, 256, 0, stream>>>((const unsigned short*)hpa16,
        WT16 + (size_t)l * 128 * 128, nnB + (size_t)l * 128, must, rstds,
        bnG + (size_t)l * 128, bnB + (size_t)l * 128, h,
        (l == 3) ? (unsigned short*)0 : hb, N);
  }
  k_poolfinal<<<GG, 256, 0, stream>>>(h, gstart, linW, linB, out);
}

// Round 9
// 1019.390 us; speedup vs baseline: 1.3067x; 1.3067x over previous
//
#include <hip/hip_runtime.h>
#include <hip/hip_fp16.h>
#include <math.h>

// Problem constants (from reference): N=100000, E=1600000, F_IN=8, H=128,
// L=4, E_FEAT=16, G=256, OUT=256. N/E derived from in_sizes at launch.
#define GG 256

typedef __attribute__((ext_vector_type(8))) short short8;
typedef __attribute__((ext_vector_type(4))) float f32x4;
typedef _Float16 half4v __attribute__((ext_vector_type(4)));
typedef __attribute__((ext_vector_type(8))) unsigned uint8v;

__device__ __forceinline__ unsigned short f2bf(float x) {
  union { float f; unsigned u; } v; v.f = x;
  unsigned r = v.u + 0x7fff + ((v.u >> 16) & 1);   // round-to-nearest-even
  return (unsigned short)(r >> 16);
}

__device__ __forceinline__ unsigned pack_h2(float a, float b) {
  __half2 h = __floats2half2_rn(a, b);
  return *(unsigned*)&h;
}

// scalar load (wave-uniform address) — SMEM path, SALU addressing
__device__ __forceinline__ uint8v sload8(const void* p) {
  uint8v r;
  asm volatile("s_load_dwordx8 %0, %1, 0x0"
               : "=s"(r) : "s"((unsigned long long)p));
  return r;
}
// drain SMEM with the pending registers tied THROUGH the asm ("+s"), so any
// consumer/copy of them is ordered after the waitcnt (SGPR-read-race safe).
__device__ __forceinline__ void swait2(uint8v& a, uint8v& b) {
  asm volatile("s_waitcnt lgkmcnt(0)" : "+s"(a), "+s"(b) :: "memory");
  __builtin_amdgcn_sched_barrier(0);
}

// ---------- h = x @ emb_W + emb_b  ([N,8]@[8,128]); also writes bf16 shadow ----------
__global__ __launch_bounds__(256) void k_emb(const float* __restrict__ x,
    const float* __restrict__ W, const float* __restrict__ b,
    float* __restrict__ h, unsigned short* __restrict__ hb, int N) {
  int idx = blockIdx.x * 256 + threadIdx.x;      // one float4 of output per thread
  if (idx >= N * 32) return;
  int n = idx >> 5, q = idx & 31;
  const float* xr = x + (size_t)n * 8;
  float xs[8];
#pragma unroll
  for (int k = 0; k < 8; ++k) xs[k] = xr[k];
  float4 acc = ((const float4*)b)[q];
#pragma unroll
  for (int k = 0; k < 8; ++k) {
    float4 w = ((const float4*)(W + (size_t)k * 128))[q];
    acc.x += xs[k] * w.x; acc.y += xs[k] * w.y;
    acc.z += xs[k] * w.z; acc.w += xs[k] * w.w;
  }
  ((float4*)h)[idx] = acc;
  ushort4 hv4 = make_ushort4(f2bf(acc.x), f2bf(acc.y), f2bf(acc.z), f2bf(acc.w));
  *(ushort4*)(hb + (size_t)idx * 4) = hv4;
}

// ---------- edge weights -> MFMA B-fragment order (fp16) ----------
// eWf[l][nt][lane] = 2 uints = 4 halves: W[l][quad*4+i][nt*16+l15], i=0..3
__global__ __launch_bounds__(256) void k_wconv2(const float* __restrict__ eW,
    unsigned* __restrict__ eWf) {              // 4*8*64 uint2 = 4096 uints
  int i = blockIdx.x * 256 + threadIdx.x;      // one uint2 per thread
  if (i >= 2048) return;
  int lane = i & 63, nt = (i >> 6) & 7, l = i >> 9;
  int l15 = lane & 15, quad = lane >> 4;
  const float* base = eW + (size_t)l * 16 * 128 + (size_t)(nt * 16 + l15);
  unsigned lo = pack_h2(base[(quad * 4 + 0) * 128], base[(quad * 4 + 1) * 128]);
  unsigned hi = pack_h2(base[(quad * 4 + 2) * 128], base[(quad * 4 + 3) * 128]);
  eWf[(size_t)i * 2] = lo;
  eWf[(size_t)i * 2 + 1] = hi;
}

// ---------- transpose nn_W to bf16: WT[l][n][k] = bf16(nn_W[l][k][n]) ----------
__global__ __launch_bounds__(256) void k_nnconv(const float* __restrict__ W,
    unsigned short* __restrict__ WT) {
  int i = blockIdx.x * 256 + threadIdx.x;    // i = ((l*128)+k)*128 + n
  if (i >= 4 * 128 * 128) return;
  int n = i & 127, k = (i >> 7) & 127, l = i >> 14;
  WT[((size_t)(l * 128 + n)) * 128 + k] = f2bf(W[i]);
}

// ---------- CSR build ----------
__global__ void k_hist(const int* __restrict__ dst, int* __restrict__ deg, int E) {
  int e = blockIdx.x * blockDim.x + threadIdx.x;
  if (e < E) atomicAdd(&deg[dst[e]], 1);
}

__global__ __launch_bounds__(256) void k_scan_reduce(const int* __restrict__ deg,
    int* __restrict__ bsum, int N) {
  __shared__ int sd[256];
  int i = blockIdx.x * 256 + threadIdx.x;
  sd[threadIdx.x] = (i < N) ? deg[i] : 0;
  __syncthreads();
  for (int s = 128; s > 0; s >>= 1) {
    if (threadIdx.x < s) sd[threadIdx.x] += sd[threadIdx.x + s];
    __syncthreads();
  }
  if (threadIdx.x == 0) bsum[blockIdx.x] = sd[0];
}

// single-block exclusive scan over nb (<=512) block sums
__global__ __launch_bounds__(512) void k_scan_mid(int* bsum, int nb) {
  __shared__ int sd[512];
  int t = threadIdx.x;
  int v = (t < nb) ? bsum[t] : 0;
  sd[t] = v; __syncthreads();
  for (int d = 1; d < 512; d <<= 1) {
    int xv = (t >= d) ? sd[t - d] : 0;
    __syncthreads();
    sd[t] += xv;
    __syncthreads();
  }
  if (t < nb) bsum[t] = sd[t] - v;   // exclusive
}

__global__ __launch_bounds__(256) void k_scan_final(const int* __restrict__ deg,
    const int* __restrict__ bsum, int* __restrict__ offs,
    int* __restrict__ cursor, int N) {
  __shared__ int sd[256];
  int t = threadIdx.x;
  int i = blockIdx.x * 256 + t;
  int v = (i < N) ? deg[i] : 0;
  sd[t] = v; __syncthreads();
  for (int d = 1; d < 256; d <<= 1) {           // Hillis-Steele inclusive scan
    int xv = (t >= d) ? sd[t - d] : 0;
    __syncthreads();
    sd[t] += xv;
    __syncthreads();
  }
  int off = bsum[blockIdx.x] + sd[t] - v;       // exclusive
  if (i < N) {
    offs[i] = off; cursor[i] = off;
    if (i == N - 1) offs[N] = off + v;
  }
}

// fill CSR: permute src + attr (converted to fp16, 32 B/edge) into dst order
__global__ void k_fill(const int* __restrict__ src, const int* __restrict__ dst,
    const float* __restrict__ attr, int* __restrict__ cursor,
    int* __restrict__ csrc, uint4* __restrict__ cattr16, int E) {
  int e = blockIdx.x * blockDim.x + threadIdx.x;
  if (e >= E) return;
  int d = dst[e];
  int pos = atomicAdd(&cursor[d], 1);
  csrc[pos] = src[e];
  const float4* a = (const float4*)(attr + (size_t)e * 16);
  float4 a0 = a[0], a1 = a[1], a2 = a[2], a3 = a[3];
  uint4 o0, o1;
  o0.x = pack_h2(a0.x, a0.y); o0.y = pack_h2(a0.z, a0.w);
  o0.z = pack_h2(a1.x, a1.y); o0.w = pack_h2(a1.z, a1.w);
  o1.x = pack_h2(a2.x, a2.y); o1.y = pack_h2(a2.z, a2.w);
  o1.z = pack_h2(a3.x, a3.y); o1.w = pack_h2(a3.z, a3.w);
  cattr16[(size_t)pos * 2] = o0;
  cattr16[(size_t)pos * 2 + 1] = o1;
}

// ---------- graph boundaries (batch is sorted) ----------
__global__ void k_gstart(const int* __restrict__ batch, int* __restrict__ gstart,
                         int N, int Gn) {
  int i = blockIdx.x * blockDim.x + threadIdx.x;
  if (i >= N) return;
  int b = batch[i];
  if (i == 0) { for (int g = 0; g <= b; ++g) gstart[g] = 0; }
  else { int bp = batch[i - 1]; for (int g = bp + 1; g <= b; ++g) gstart[g] = i; }
  if (i == N - 1) { for (int g = b + 1; g <= Gn; ++g) gstart[g] = N; }
}

// ---------- fused edge embed + gather + relu + aggregate (v9) ----------
// hpa16[n] = bf16( hb[n] + sum_j relu( attr[j]@edge_W + edge_b + hb[src[j]] ) )
// = round-7 v7 structure, but the residual term reads the bf16 shadow hb
// (4 B/lane) instead of fp32 h (8 B/lane): -51 MB HBM per dispatch.
__global__ __launch_bounds__(256) void k_edge_agg(
    const unsigned* __restrict__ hb32,       // bf16 shadow viewed as uint
    const uint4* __restrict__ cattr16, const int* __restrict__ csrc,
    const int* __restrict__ offs, const unsigned* __restrict__ eWf,
    const float* __restrict__ eb, unsigned* __restrict__ hpa16,
    float* __restrict__ cstats, int N) {
  __shared__ __half elds_all[4][16 * 136];
  int t = threadIdx.x;
  if (blockIdx.x == 0) cstats[t] = 0.f;    // 256 floats: colsum|colsumsq
  int lane = t & 63;                        // lane -> columns 2*lane, 2*lane+1
  int l15 = lane & 15, quad = lane >> 4;
  int wid = blockIdx.x * 4 + (t >> 6);
  int nw = gridDim.x * 4;
  __half* elds = elds_all[t >> 6];
  uint2 bfr[8];                             // B-fragments (whole W in regs)
#pragma unroll
  for (int nt = 0; nt < 8; ++nt) bfr[nt] = ((const uint2*)eWf)[nt * 64 + lane];
  float2 bias = *(const float2*)(eb + 2 * lane);
  const unsigned* hb_l = hb32 + lane;       // + s*64 per edge (row = 64 uints)

#define GI(r, SC)                                                           \
  unsigned u##r = 0;                                                        \
  if (j0 + (r) < je) u##r = hb_l[(size_t)(unsigned)(SC) * 64];

#define EPI(r, UU, AX, AY)                                                  \
  if (j0 + (r) < je) {                                                      \
    __half2 ev2 = *(__half2*)&elds[(r) * 136 + 2 * lane];                   \
    union { unsigned uu; float ff; } c0, c1;                                \
    c0.uu = (UU) << 16; c1.uu = (UU) & 0xffff0000u;                         \
    AX += fmaxf(__low2float(ev2) + bias.x + c0.ff, 0.f);                    \
    AY += fmaxf(__high2float(ev2) + bias.y + c1.ff, 0.f);                   \
  }

#define LOADA(DST, J0)                                                      \
  DST = *(const uint2*)((const char*)cattr16 +                              \
        ((size_t)(unsigned)((J0) + l15)) * 32 + quad * 8);

  for (int n = wid; n < N; n += nw) {
    int jb = __builtin_amdgcn_readfirstlane(offs[n]);
    int je = __builtin_amdgcn_readfirstlane(offs[n + 1]);
    float ax = 0.f, ay = 0.f, bx = 0.f, by = 0.f;
    if (jb < je) {
      uint8v scA = sload8((const char*)csrc + ((size_t)(unsigned)jb << 2));
      uint8v scB = sload8((const char*)csrc + ((size_t)(unsigned)(jb + 8) << 2));
      uint2 araw;
      LOADA(araw, jb)
      swait2(scA, scB);
      for (int j0 = jb;;) {
        GI(0, scA[0]) GI(1, scA[1]) GI(2, scA[2]) GI(3, scA[3])
        GI(4, scA[4]) GI(5, scA[5]) GI(6, scA[6]) GI(7, scA[7])
        GI(8, scB[0]) GI(9, scB[1]) GI(10, scB[2]) GI(11, scB[3])
        GI(12, scB[4]) GI(13, scB[5]) GI(14, scB[6]) GI(15, scB[7])
        bool more = (j0 + 16 < je);
        uint8v scA2, scB2;
        uint2 araw2;
        if (more) {
          scA2 = sload8((const char*)csrc + ((size_t)(unsigned)(j0 + 16) << 2));
          scB2 = sload8((const char*)csrc + ((size_t)(unsigned)(j0 + 24) << 2));
          LOADA(araw2, j0 + 16)
        }
        half4v av;
        __builtin_memcpy(&av, &araw, 8);
        f32x4 ee[8];
#pragma unroll
        for (int nt = 0; nt < 8; ++nt) {
          half4v bv;
          __builtin_memcpy(&bv, &bfr[nt], 8);
          ee[nt] = __builtin_amdgcn_mfma_f32_16x16x16f16(
              av, bv, (f32x4){0.f, 0.f, 0.f, 0.f}, 0, 0, 0);
        }
#pragma unroll
        for (int nt = 0; nt < 8; ++nt)
#pragma unroll
          for (int reg = 0; reg < 4; ++reg)
            elds[(quad * 4 + reg) * 136 + nt * 16 + l15] =
                __float2half(ee[nt][reg]);
        EPI(0, u0, ax, ay)  EPI(1, u1, bx, by)
        EPI(2, u2, ax, ay)  EPI(3, u3, bx, by)
        EPI(4, u4, ax, ay)  EPI(5, u5, bx, by)
        EPI(6, u6, ax, ay)  EPI(7, u7, bx, by)
        EPI(8, u8, ax, ay)  EPI(9, u9, bx, by)
        EPI(10, u10, ax, ay) EPI(11, u11, bx, by)
        EPI(12, u12, ax, ay) EPI(13, u13, bx, by)
        EPI(14, u14, ax, ay) EPI(15, u15, bx, by)
        j0 += 16;
        if (!more) break;
        swait2(scA2, scB2);
        scA = scA2; scB = scB2; araw = araw2;
      }
    }
    // residual from bf16 shadow (4 B/lane, coalesced 256 B/row)
    unsigned hv = hb32[(size_t)n * 64 + lane];
    union { unsigned uu; float ff; } r0, r1;
    r0.uu = hv << 16; r1.uu = hv & 0xffff0000u;
    float rx = r0.ff + ax + bx;
    float ry = r1.ff + ay + by;
    hpa16[(size_t)n * 64 + lane] = ((unsigned)f2bf(ry) << 16) | (unsigned)f2bf(rx);
  }
#undef GI
#undef EPI
#undef LOADA
}

// ---------- MFMA node GEMM: hc = bf16(hpa) @ nn_W + nn_b, + fused BN stats ----------
// 128 rows/block, 4 waves x (2 row-tiles x 8 col-tiles) of 16x16x32 bf16 MFMA.
// A and WT (pre-transposed W, [n][k]) staged in LDS, rows padded +8 shorts
// (272 B stride -> 2-way bank aliasing, free). Stats: shfl-xor quad reduce ->
// LDS -> 256 atomics per block.
__global__ __launch_bounds__(256) void k_gemm_mfma(
    const unsigned short* __restrict__ A16, const unsigned short* __restrict__ WT16,
    const float* __restrict__ bias, float* __restrict__ hc,
    float* __restrict__ cstats, int N) {
  __shared__ short a_lds[128 * 136];
  __shared__ short w_lds[128 * 136];
  int t = threadIdx.x;
  int rowbase = blockIdx.x * 128;
  {
    int r = t >> 1;
    int off = (t & 1) * 64;              // shorts
    const short* ga = (const short*)A16 + (size_t)(rowbase + r) * 128 + off;
    short* la = &a_lds[r * 136 + off];
    const short* gw = (const short*)WT16 + (size_t)r * 128 + off;
    short* lw = &w_lds[r * 136 + off];
    if (rowbase + r < N) {
#pragma unroll
      for (int jj = 0; jj < 8; ++jj)
        *(uint4*)(la + jj * 8) = *(const uint4*)(ga + jj * 8);
    } else {
#pragma unroll
      for (int jj = 0; jj < 8; ++jj)
        *(uint4*)(la + jj * 8) = make_uint4(0, 0, 0, 0);
    }
#pragma unroll
    for (int jj = 0; jj < 8; ++jj)
      *(uint4*)(lw + jj * 8) = *(const uint4*)(gw + jj * 8);
  }
  __syncthreads();
  int w = t >> 6;
  int lane = t & 63;
  int l15 = lane & 15, quad = lane >> 4;
  f32x4 acc[2][8];
#pragma unroll
  for (int rt = 0; rt < 2; ++rt)
#pragma unroll
    for (int nt = 0; nt < 8; ++nt)
      acc[rt][nt] = (f32x4){0.f, 0.f, 0.f, 0.f};
#pragma unroll
  for (int kc = 0; kc < 4; ++kc) {
    int k0 = kc * 32 + quad * 8;
    short8 af0 = *(const short8*)&a_lds[(w * 32 + l15) * 136 + k0];
    short8 af1 = *(const short8*)&a_lds[(w * 32 + 16 + l15) * 136 + k0];
#pragma unroll
    for (int nt = 0; nt < 8; ++nt) {
      short8 bf = *(const short8*)&w_lds[(nt * 16 + l15) * 136 + k0];
      acc[0][nt] = __builtin_amdgcn_mfma_f32_16x16x32_bf16(af0, bf, acc[0][nt], 0, 0, 0);
      acc[1][nt] = __builtin_amdgcn_mfma_f32_16x16x32_bf16(af1, bf, acc[1][nt], 0, 0, 0);
    }
  }
  float sA[8], sQ[8];
#pragma unroll
  for (int nt = 0; nt < 8; ++nt) { sA[nt] = 0.f; sQ[nt] = 0.f; }
#pragma unroll
  for (int nt = 0; nt < 8; ++nt) {
    int col = nt * 16 + l15;
    float bv = bias[col];
#pragma unroll
    for (int rt = 0; rt < 2; ++rt) {
      int rbase = rowbase + w * 32 + rt * 16 + quad * 4;
#pragma unroll
      for (int reg = 0; reg < 4; ++reg) {
        int row = rbase + reg;
        float v = acc[rt][nt][reg] + bv;
        if (row < N) {
          hc[(size_t)row * 128 + col] = v;
          sA[nt] += v; sQ[nt] += v * v;
        }
      }
    }
  }
#pragma unroll
  for (int nt = 0; nt < 8; ++nt) {
    sA[nt] += __shfl_xor(sA[nt], 16);
    sA[nt] += __shfl_xor(sA[nt], 32);
    sQ[nt] += __shfl_xor(sQ[nt], 16);
    sQ[nt] += __shfl_xor(sQ[nt], 32);
  }
  __syncthreads();                    // done with a_lds/w_lds contents
  float* sdA = (float*)a_lds;         // [4][128]
  float* sdQ = (float*)w_lds;
  if (quad == 0) {
#pragma unroll
    for (int nt = 0; nt < 8; ++nt) {
      sdA[w * 128 + nt * 16 + l15] = sA[nt];
      sdQ[w * 128 + nt * 16 + l15] = sQ[nt];
    }
  }
  __syncthreads();
  if (t < 128) {
    float s = sdA[t] + sdA[128 + t] + sdA[256 + t] + sdA[384 + t];
    float s2 = sdQ[t] + sdQ[128 + t] + sdQ[256 + t] + sdQ[384 + t];
    atomicAdd(&cstats[t], s);
    atomicAdd(&cstats[128 + t], s2);
  }
}

// ---------- BN apply + exact GELU + residual: h += gelu(bn(hc)); bf16 shadow ----------
__global__ __launch_bounds__(256) void k_bn(const float* __restrict__ hc,
    const float* __restrict__ cstats,
    const float* __restrict__ g, const float* __restrict__ bb,
    float* __restrict__ h, unsigned short* __restrict__ hb, int N) {
  int idx = blockIdx.x * 256 + threadIdx.x;
  if (idx >= N * 32) return;
  int q = idx & 31;
  float invN = 1.f / (float)N;
  float4 cs = ((const float4*)cstats)[q];
  float4 cq = ((const float4*)cstats)[q + 32];
  float4 gv = ((const float4*)g)[q];
  float4 bv = ((const float4*)bb)[q];
  float4 v = ((const float4*)hc)[idx];
  float4 hv = ((const float4*)h)[idx];
#define BN1(X)                                                      \
  { float mu = cs.X * invN;                                         \
    float var = cq.X * invN - mu * mu;                              \
    float xn = (v.X - mu) * rsqrtf(var + 1e-5f) * gv.X + bv.X;      \
    hv.X += 0.5f * xn * (1.f + erff(xn * 0.70710678118654752f)); }
  BN1(x) BN1(y) BN1(z) BN1(w)
#undef BN1
  ((float4*)h)[idx] = hv;
  if (hb) {
    ushort4 hv4 = make_ushort4(f2bf(hv.x), f2bf(hv.y), f2bf(hv.z), f2bf(hv.w));
    *(ushort4*)(hb + (size_t)idx * 4) = hv4;
  }
}

// ---------- rep[g] = (sum over nodes of graph g of h[n]) @ lin_W + cnt*lin_b ----------
__global__ __launch_bounds__(256) void k_poolfinal(const float* __restrict__ h,
    const int* __restrict__ gstart, const float* __restrict__ W,
    const float* __restrict__ b, float* __restrict__ out) {
  int g = blockIdx.x;
  int t = threadIdx.x, c = t & 127, half = t >> 7;
  int n0 = gstart[g], n1 = gstart[g + 1];
  float s = 0.f;
  for (int n = n0 + half; n < n1; n += 2) s += h[(size_t)n * 128 + c];
  __shared__ float ls[256];
  __shared__ float pr[128];
  ls[t] = s; __syncthreads();
  if (t < 128) pr[t] = ls[t] + ls[t + 128];
  __syncthreads();
  float cnt = (float)(n1 - n0);
  float acc = cnt * b[t];
#pragma unroll 8
  for (int k = 0; k < 128; ++k) acc += pr[k] * W[(size_t)k * 256 + t];
  out[(size_t)g * 256 + t] = acc;
}

extern "C" void kernel_launch(void* const* d_in, const int* in_sizes, int n_in,
                              void* d_out, int out_size, void* d_ws, size_t ws_size,
                              hipStream_t stream) {
  const float* x     = (const float*)d_in[0];
  const int*   eidx  = (const int*)d_in[1];
  const float* eattr = (const float*)d_in[2];
  const int*   batch = (const int*)d_in[3];
  const float* embW  = (const float*)d_in[4];
  const float* embB  = (const float*)d_in[5];
  const float* edgeW = (const float*)d_in[6];
  const float* edgeB = (const float*)d_in[7];
  const float* nnW   = (const float*)d_in[8];
  const float* nnB   = (const float*)d_in[9];
  const float* bnG   = (const float*)d_in[10];
  const float* bnB   = (const float*)d_in[11];
  const float* linW  = (const float*)d_in[12];
  const float* linB  = (const float*)d_in[13];
  float* out = (float*)d_out;

  int N = in_sizes[0] / 8;
  int E = in_sizes[1] / 2;
  const int* src = eidx;
  const int* dst = eidx + E;

  // workspace carve-up; cattr16/csrc get 16-edge slack for masked group loads.
  char* wptr = (char*)d_ws;
  auto alloc = [&](size_t bytes) {
    char* p = wptr; wptr += (bytes + 255) & ~(size_t)255; return p;
  };
  float* h      = (float*)alloc((size_t)N * 128 * 4);
  float* hc     = (float*)alloc((size_t)N * 128 * 4);   // fp32 GEMM output
  unsigned short* hb = (unsigned short*)alloc((size_t)N * 128 * 2);  // bf16 h shadow
  unsigned* hpa16 = (unsigned*)alloc((size_t)N * 64 * 4);  // bf16 h+agg (GEMM input)
  uint4* cattr16 = (uint4*)alloc((size_t)E * 32 + 1024); // fp16 attrs + slack
  int*   csrc   = (int*)alloc((size_t)E * 4 + 256);      // + slack
  int*   offs   = (int*)alloc((size_t)(N + 1) * 4);
  int*   cursor = (int*)alloc((size_t)N * 4);
  int*   deg    = (int*)alloc((size_t)N * 4);
  int nb = (N + 255) / 256;
  int*   bsum   = (int*)alloc((size_t)nb * 4);
  float* cstats = (float*)alloc(256 * 4);               // colsum | colsumsq
  unsigned* eWf = (unsigned*)alloc(4096 * 4);           // [4][8][64] B-frag uint2
  unsigned short* WT16 = (unsigned short*)alloc(4 * 128 * 128 * 2);  // bf16 W^T
  int*   gstart = (int*)alloc((size_t)(GG + 1) * 4);

  int q32 = (N * 32 + 255) / 256;

  hipMemsetAsync(deg, 0, (size_t)N * 4, stream);
  k_emb<<<q32, 256, 0, stream>>>(x, embW, embB, h, hb, N);
  k_wconv2<<<8, 256, 0, stream>>>(edgeW, eWf);
  k_nnconv<<<256, 256, 0, stream>>>(nnW, WT16);
  k_hist<<<(E + 255) / 256, 256, 0, stream>>>(dst, deg, E);
  k_scan_reduce<<<nb, 256, 0, stream>>>(deg, bsum, N);
  k_scan_mid<<<1, 512, 0, stream>>>(bsum, nb);
  k_scan_final<<<nb, 256, 0, stream>>>(deg, bsum, offs, cursor, N);
  k_fill<<<(E + 255) / 256, 256, 0, stream>>>(src, dst, eattr, cursor, csrc, cattr16, E);
  k_gstart<<<(N + 255) / 256, 256, 0, stream>>>(batch, gstart, N, GG);

  int gblk = (N + 127) / 128;
  for (int l = 0; l < 4; ++l) {
    k_edge_agg<<<8192, 256, 0, stream>>>((const unsigned*)hb, cattr16, csrc,
        offs, eWf + (size_t)l * 1024, edgeB + (size_t)l * 128, hpa16, cstats, N);
    k_gemm_mfma<<<gblk, 256, 0, stream>>>((const unsigned short*)hpa16,
        WT16 + (size_t)l * 128 * 128, nnB + (size_t)l * 128, hc, cstats, N);
    k_bn<<<q32, 256, 0, stream>>>(hc, cstats,
        bnG + (size_t)l * 128, bnB + (size_t)l * 128, h, (l == 3) ? nullptr : hb, N);
  }
  k_poolfinal<<<GG, 256, 0, stream>>>(h, gstart, linW, linB, out);
}